// Round 16
// baseline (2770.781 us; speedup 1.0000x reference)
//
#include <hip/hip_runtime.h>

#define NODES 10000
#define EDGES 160000
#define INF_ 16
#define DD 512
#define GRAPHS 64
#define NOUT 18
#define BN_EPS 1e-5f
#define NBUCK 8
#define LSTRIDE 80
#define NBLK 628

using u16 = unsigned short;
typedef __attribute__((ext_vector_type(8))) _Float16 f16x8;
typedef __attribute__((ext_vector_type(4))) float f32x4;

__device__ __forceinline__ float h2f(u16 u) {
  union { u16 u; _Float16 h; } v; v.u = u; return (float)v.h;
}
__device__ __forceinline__ u16 f2h(float f) {
  union { u16 u; _Float16 h; } v; v.h = (_Float16)f; return v.u;
}
__device__ __forceinline__ void add8(uint4 u, float* a) {
  a[0] += h2f((u16)(u.x & 0xffff)); a[1] += h2f((u16)(u.x >> 16));
  a[2] += h2f((u16)(u.y & 0xffff)); a[3] += h2f((u16)(u.y >> 16));
  a[4] += h2f((u16)(u.z & 0xffff)); a[5] += h2f((u16)(u.z >> 16));
  a[6] += h2f((u16)(u.w & 0xffff)); a[7] += h2f((u16)(u.w >> 16));
}
__device__ __forceinline__ unsigned int pk(float a, float b) {
  return (unsigned int)f2h(a) | ((unsigned int)f2h(b) << 16);
}
__device__ __forceinline__ int lower_bound_dev(const int* __restrict__ batch, int g) {
  int lo = 0, hi = NODES;
  while (lo < hi) { int m = (lo + hi) >> 1; if (batch[m] < g) lo = m + 1; else hi = m; }
  return lo;
}

// ---- hand-rolled grid barrier (all NBLK blocks co-resident by construction) ----
__device__ __forceinline__ void gridbar(int* bar, int idx) {
  __syncthreads();
  if (threadIdx.x == 0) {
    __threadfence();  // release: write back this XCD's L2 (agent scope)
    __hip_atomic_fetch_add(&bar[idx], 1, __ATOMIC_RELEASE, __HIP_MEMORY_SCOPE_AGENT);
    while (__hip_atomic_load(&bar[idx], __ATOMIC_ACQUIRE, __HIP_MEMORY_SCOPE_AGENT) < NBLK)
      __builtin_amdgcn_s_sleep(1);
    __threadfence();  // acquire: invalidate L1/L2 before dependent reads
  }
  __syncthreads();
}

// ---- setup: zero cur (10000 i32) + bns|gsum (73728 f) + bar (16 i32) ----
__global__ void k_setup(int* __restrict__ cur, float* __restrict__ bg, int* __restrict__ bar) {
  int i = blockIdx.x * 256 + threadIdx.x;
  if (i < NODES) cur[i] = 0;
  if (i < 73728) bg[i] = 0.f;
  if (i < 16) bar[i] = 0;
}

// ---- CSR build (dst-indexed): count -> scan(+reset) -> fill ----
__global__ void k_count(const int* __restrict__ dst, int* __restrict__ cnt) {
  int e = blockIdx.x * 256 + threadIdx.x;
  if (e < EDGES) atomicAdd(&cnt[dst[e]], 1);
}

__global__ __launch_bounds__(1024) void k_scan(int* __restrict__ cnt, int* __restrict__ rowptr) {
  __shared__ int s[1024];
  int t = threadIdx.x;
  int base = t * 10;
  int c[10]; int sum = 0;
#pragma unroll
  for (int i = 0; i < 10; ++i) {
    int idx = base + i;
    c[i] = (idx < NODES) ? cnt[idx] : 0;
    if (idx < NODES) cnt[idx] = 0;
    sum += c[i];
  }
  s[t] = sum; __syncthreads();
  for (int off = 1; off < 1024; off <<= 1) {
    int v = s[t];
    int a = (t >= off) ? s[t - off] : 0;
    __syncthreads();
    s[t] = v + a;
    __syncthreads();
  }
  int run = (t == 0) ? 0 : s[t - 1];
#pragma unroll
  for (int i = 0; i < 10; ++i) { int idx = base + i; if (idx < NODES) rowptr[idx] = run; run += c[i]; }
  if (t == 1023) rowptr[NODES] = s[1023];
}

__global__ void k_fill(const int* __restrict__ src, const int* __restrict__ dst,
                       const int* __restrict__ rowptr, int* __restrict__ cur, int* __restrict__ col) {
  int e = blockIdx.x * 256 + threadIdx.x;
  if (e < EDGES) {
    int d = dst[e];
    int p = atomicAdd(&cur[d], 1);
    col[rowptr[d] + p] = src[e];
  }
}

// ---- W transpose to fp16 [n][k]: Wt[n][k] = W[k][n] ----
__global__ __launch_bounds__(256) void k_wsplit(const float* __restrict__ W1b, const float* __restrict__ Wa,
                                                const float* __restrict__ Wb, u16* __restrict__ Wt) {
  __shared__ float tile[32][33];
  int z = blockIdx.z;
  const float* src = (z == 0) ? W1b : (z <= 4 ? Wa + (z - 1) * DD * DD : Wb + (z - 5) * DD * DD);
  int kb = blockIdx.y * 32, nb = blockIdx.x * 32;
  int tx = threadIdx.x & 31, ty = threadIdx.x >> 5;  // 32 x 8
#pragma unroll
  for (int i = 0; i < 4; ++i)
    tile[ty + 8 * i][tx] = src[(kb + ty + 8 * i) * DD + nb + tx];
  __syncthreads();
  u16* hi = Wt + (size_t)z * 262144;
#pragma unroll
  for (int i = 0; i < 4; ++i) {
    int n = nb + ty + 8 * i, k = kb + tx;
    hi[n * DD + k] = f2h(tile[tx][ty + 8 * i]);
  }
}

// ---- layer 1 fused: agg16 (LDS) + relu(h0 @ W1a + b1a), fp16 out ----
__global__ __launch_bounds__(256) void k_l1(const float* __restrict__ x, const int* __restrict__ rowptr,
                                            const int* __restrict__ col, const float* __restrict__ W1a,
                                            const float* __restrict__ b1a, u16* __restrict__ out) {
  __shared__ float sh0[16][17];
  int t = threadIdx.x;
  int nl = t >> 4, ch = t & 15;
  int node = blockIdx.x * 16 + nl;   // 625*16 = 10000 exact
  float acc = x[node * INF_ + ch];
  int r1 = rowptr[node + 1];
  for (int idx = rowptr[node]; idx < r1; ++idx)
    acc += x[col[idx] * INF_ + ch];
  sh0[nl][ch] = acc;
  __syncthreads();
#pragma unroll
  for (int p = 0; p < 2; ++p) {
    int c = t + 256 * p;
    float wreg[16];
#pragma unroll
    for (int k = 0; k < 16; ++k) wreg[k] = W1a[k * DD + c];
    float bv = b1a[c];
#pragma unroll
    for (int r = 0; r < 16; ++r) {
      float s = bv;
#pragma unroll
      for (int k = 0; k < 16; ++k) s = fmaf(sh0[r][k], wreg[k], s);
      out[(size_t)(blockIdx.x * 16 + r) * DD + c] = f2h(fmaxf(s, 0.f));
    }
  }
}

// ---- gemm stage (device fn): C = relu(A @ W + bias), optional bucketed BN stats ----
__device__ __forceinline__ void gemm_stage(
    const u16* __restrict__ A, const u16* __restrict__ Wt,
    const float* __restrict__ bias, u16* __restrict__ C,
    float* __restrict__ stats, int doStats, u16* smem) {
  u16* As = smem;                      // [64][80]
  u16* Wh = smem + 64 * LSTRIDE;       // [128][80]
  const int T = threadIdx.x;
  int id = blockIdx.x;
  int bm_i, bn_i;
  if (id < 608) { int gi = id >> 5, r = id & 31; bm_i = gi * 8 + (r & 7); bn_i = r >> 3; }
  else { int r = id - 608; bm_i = 152 + (r % 5); bn_i = r / 5; }
  const int bm = bm_i * 64;
  const int bn = bn_i * 128;
  const int lane = T & 63;
  const int wave = T >> 6;
  const int wm = (wave & 1) * 32;
  const int wn = (wave >> 1) * 64;
  const int q = lane >> 4;
  const int r16 = lane & 15;

  const int arow0 = bm + (T >> 3);
  const int akc = (T & 7) * 8;
  f32x4 acc[2][4] = {};

  uint4 ra[2], rw[4];
#pragma unroll
  for (int p = 0; p < 2; ++p) {
    int grow = arow0 + p * 32;
    ra[p] = make_uint4(0u, 0u, 0u, 0u);
    if (grow < NODES) ra[p] = *(const uint4*)(A + (size_t)grow * DD + akc);
  }
#pragma unroll
  for (int p = 0; p < 4; ++p) {
    int row = (T + 256 * p) >> 3;
    rw[p] = *(const uint4*)(Wt + (size_t)(bn + row) * DD + akc);
  }

  for (int k0 = 0; k0 < 512; k0 += 64) {
#pragma unroll
    for (int p = 0; p < 2; ++p) {
      int row = (T >> 3) + p * 32;
      *(uint4*)(As + row * LSTRIDE + akc) = ra[p];
    }
#pragma unroll
    for (int p = 0; p < 4; ++p) {
      int row = (T + 256 * p) >> 3;
      *(uint4*)(Wh + row * LSTRIDE + akc) = rw[p];
    }
    __syncthreads();
    if (k0 + 64 < 512) {
      int kn = k0 + 64;
#pragma unroll
      for (int p = 0; p < 2; ++p) {
        int grow = arow0 + p * 32;
        ra[p] = make_uint4(0u, 0u, 0u, 0u);
        if (grow < NODES) ra[p] = *(const uint4*)(A + (size_t)grow * DD + kn + akc);
      }
#pragma unroll
      for (int p = 0; p < 4; ++p) {
        int row = (T + 256 * p) >> 3;
        rw[p] = *(const uint4*)(Wt + (size_t)(bn + row) * DD + kn + akc);
      }
    }
#pragma unroll
    for (int ks = 0; ks < 2; ++ks) {
      int kb = ks * 32 + q * 8;
      f16x8 af[2], bh[4];
#pragma unroll
      for (int mt = 0; mt < 2; ++mt)
        af[mt] = *(const f16x8*)(As + (wm + mt * 16 + r16) * LSTRIDE + kb);
#pragma unroll
      for (int nt = 0; nt < 4; ++nt)
        bh[nt] = *(const f16x8*)(Wh + (wn + nt * 16 + r16) * LSTRIDE + kb);
#pragma unroll
      for (int mt = 0; mt < 2; ++mt)
#pragma unroll
        for (int nt = 0; nt < 4; ++nt)
          acc[mt][nt] = __builtin_amdgcn_mfma_f32_16x16x32_f16(af[mt], bh[nt], acc[mt][nt], 0, 0, 0);
    }
    __syncthreads();
  }

  float colS[4] = {}, colQ[4] = {};
#pragma unroll
  for (int nt = 0; nt < 4; ++nt) {
    int n = bn + wn + nt * 16 + r16;
    float bv = bias[n];
#pragma unroll
    for (int mt = 0; mt < 2; ++mt) {
#pragma unroll
      for (int rr = 0; rr < 4; ++rr) {
        int row = bm + wm + mt * 16 + q * 4 + rr;
        if (row < NODES) {
          float v = fmaxf(acc[mt][nt][rr] + bv, 0.f);
          C[(size_t)row * DD + n] = f2h(v);
          if (doStats) { colS[nt] += v; colQ[nt] += v * v; }
        }
      }
    }
  }
  if (doStats) {
#pragma unroll
    for (int nt = 0; nt < 4; ++nt) {
      colS[nt] += __shfl_xor(colS[nt], 16); colS[nt] += __shfl_xor(colS[nt], 32);
      colQ[nt] += __shfl_xor(colQ[nt], 16); colQ[nt] += __shfl_xor(colQ[nt], 32);
    }
    float* lsum = (float*)smem;          // [4][64]
    float* lsq = lsum + 256;             // [4][64]
    if (q == 0) {
#pragma unroll
      for (int nt = 0; nt < 4; ++nt) {
        lsum[wave * 64 + nt * 16 + r16] = colS[nt];
        lsq[wave * 64 + nt * 16 + r16] = colQ[nt];
      }
    }
    __syncthreads();
    if (T < 128) {
      int c = T;
      int wb = (c >> 6) << 1;
      int cc = c & 63;
      float s = lsum[wb * 64 + cc] + lsum[(wb + 1) * 64 + cc];
      float qv = lsq[wb * 64 + cc] + lsq[(wb + 1) * 64 + cc];
      float* sb = stats + (size_t)(bm_i & (NBUCK - 1)) * 1024;
      atomicAdd(&sb[bn + c], s);
      atomicAdd(&sb[512 + bn + c], qv);
    }
    __syncthreads();   // protect smem before next stage reuses it
  }
}

// ---- agg stage (device fn): T = bn(gather(H)), grid-strided wave-per-node ----
__device__ __forceinline__ void agg_stage(
    const u16* __restrict__ H, const int* __restrict__ rowptr, const int* __restrict__ col,
    const float* __restrict__ stats, const float* __restrict__ gamma, const float* __restrict__ beta,
    u16* __restrict__ T_out, float* smemf) {
  float* ssc = smemf;        // [512]
  float* ssh = smemf + 512;  // [512]
  int t = threadIdx.x;
#pragma unroll
  for (int r = 0; r < 2; ++r) {
    int c = t + r * 256;
    float s = 0.f, qv = 0.f;
#pragma unroll
    for (int b = 0; b < NBUCK; ++b) {
      s += stats[b * 1024 + c];
      qv += stats[b * 1024 + 512 + c];
    }
    float mean = s * (1.f / NODES);
    float var = qv * (1.f / NODES) - mean * mean;
    float sc = gamma[c] * rsqrtf(var + BN_EPS);
    ssc[c] = sc;
    ssh[c] = beta[c] - mean * sc;
  }
  __syncthreads();

  int lane = t & 63;
  int c8 = lane * 8;
  float sc[8], sh[8];
#pragma unroll
  for (int k = 0; k < 8; ++k) { sc[k] = ssc[c8 + k]; sh[k] = ssh[c8 + k]; }
  const u16* hp = H + c8;

  for (int node = blockIdx.x * 4 + (t >> 6); node < NODES; node += 4 * NBLK) {
    float acc[8];
    {
      uint4 sv = *(const uint4*)(hp + (size_t)node * DD);
      acc[0] = h2f((u16)(sv.x & 0xffff)); acc[1] = h2f((u16)(sv.x >> 16));
      acc[2] = h2f((u16)(sv.y & 0xffff)); acc[3] = h2f((u16)(sv.y >> 16));
      acc[4] = h2f((u16)(sv.z & 0xffff)); acc[5] = h2f((u16)(sv.z >> 16));
      acc[6] = h2f((u16)(sv.w & 0xffff)); acc[7] = h2f((u16)(sv.w >> 16));
    }
    int r0 = rowptr[node], r1 = rowptr[node + 1];
    int idx = r0;
    for (; idx + 7 < r1; idx += 8) {
      int j0 = col[idx],     j1 = col[idx + 1], j2 = col[idx + 2], j3 = col[idx + 3];
      int j4 = col[idx + 4], j5 = col[idx + 5], j6 = col[idx + 6], j7 = col[idx + 7];
      uint4 a = *(const uint4*)(hp + (size_t)j0 * DD);
      uint4 b = *(const uint4*)(hp + (size_t)j1 * DD);
      uint4 c = *(const uint4*)(hp + (size_t)j2 * DD);
      uint4 d = *(const uint4*)(hp + (size_t)j3 * DD);
      uint4 e = *(const uint4*)(hp + (size_t)j4 * DD);
      uint4 f = *(const uint4*)(hp + (size_t)j5 * DD);
      uint4 g = *(const uint4*)(hp + (size_t)j6 * DD);
      uint4 hh = *(const uint4*)(hp + (size_t)j7 * DD);
      add8(a, acc); add8(b, acc); add8(c, acc); add8(d, acc);
      add8(e, acc); add8(f, acc); add8(g, acc); add8(hh, acc);
    }
    for (; idx + 1 < r1; idx += 2) {
      int j0 = col[idx], j1 = col[idx + 1];
      uint4 a = *(const uint4*)(hp + (size_t)j0 * DD);
      uint4 b = *(const uint4*)(hp + (size_t)j1 * DD);
      add8(a, acc); add8(b, acc);
    }
    if (idx < r1) {
      uint4 a = *(const uint4*)(hp + (size_t)col[idx] * DD);
      add8(a, acc);
    }
    float n = (float)(r1 - r0 + 1);
    uint4 o;
    o.x = pk(sc[0] * acc[0] + n * sh[0], sc[1] * acc[1] + n * sh[1]);
    o.y = pk(sc[2] * acc[2] + n * sh[2], sc[3] * acc[3] + n * sh[3]);
    o.z = pk(sc[4] * acc[4] + n * sh[4], sc[5] * acc[5] + n * sh[5]);
    o.w = pk(sc[6] * acc[6] + n * sh[6], sc[7] * acc[7] + n * sh[7]);
    *(uint4*)(T_out + (size_t)node * DD + c8) = o;
  }
  __syncthreads();   // protect smem before next stage reuses it
}

// ---- mega-kernel (normal launch, hand-rolled grid barriers) ----
__global__ __launch_bounds__(256, 3) void k_net(
    u16* __restrict__ P0m, u16* __restrict__ P1m,
    const int* __restrict__ rowptr, const int* __restrict__ col,
    const u16* __restrict__ Wt, const float* __restrict__ b1b,
    const float* __restrict__ ba, const float* __restrict__ bb,
    const float* __restrict__ bng, const float* __restrict__ bnb,
    float* __restrict__ bns, int* __restrict__ bar) {
  __shared__ u16 smem[15360];   // 30720 B, reused by every stage

  // stage 0: P1 = relu(P0 @ W1b + b1b), stats -> bns[0]
  gemm_stage(P0m, Wt, b1b, P1m, bns, 1, smem);
  gridbar(bar, 0);

  u16* H = P1m;
  u16* T = P0m;
#pragma unroll 1
  for (int i = 0; i < 4; ++i) {
    agg_stage(H, rowptr, col, bns + (size_t)i * NBUCK * 1024, bng + i * DD, bnb + i * DD, T, (float*)smem);
    gridbar(bar, 1 + 3 * i);
    gemm_stage(T, Wt + (size_t)(1 + i) * 262144, ba + i * DD, H, nullptr, 0, smem);
    gridbar(bar, 2 + 3 * i);
    gemm_stage(H, Wt + (size_t)(5 + i) * 262144, bb + i * DD, T, bns + (size_t)(i + 1) * NBUCK * 1024, 1, smem);
    if (i < 3) gridbar(bar, 3 + 3 * i);
    u16* tmp = H; H = T; T = tmp;
  }
  // final activations land in P1
}

// ---- pooled partial sums: grid (GRAPHS, 8 slices) ----
__global__ __launch_bounds__(128) void k_pool_part(const u16* __restrict__ h, const int* __restrict__ batch,
                                                   float* __restrict__ gsum) {
  int g = blockIdx.x;
  int s = blockIdx.y;
  int c4 = threadIdx.x * 4;
  int r0 = lower_bound_dev(batch, g);
  int r1 = lower_bound_dev(batch, g + 1);
  int cnt = r1 - r0;
  int len = (cnt + 7) >> 3;
  int rs = r0 + s * len;
  int re = min(rs + len, r1);
  if (rs >= re) return;
  float4 acc = make_float4(0.f, 0.f, 0.f, 0.f);
  for (int r = rs; r < re; ++r) {
    ushort4 v = *(const ushort4*)(h + (size_t)r * DD + c4);
    acc.x += h2f(v.x); acc.y += h2f(v.y); acc.z += h2f(v.z); acc.w += h2f(v.w);
  }
  atomicAdd(&gsum[g * DD + c4 + 0], acc.x);
  atomicAdd(&gsum[g * DD + c4 + 1], acc.y);
  atomicAdd(&gsum[g * DD + c4 + 2], acc.z);
  atomicAdd(&gsum[g * DD + c4 + 3], acc.w);
}

// ---- head: feats = tanh(bn(mean) @ Wfc + bfc); grid (GRAPHS, 8 col-slices), K split 4-way ----
__global__ __launch_bounds__(256) void k_headf(const float* __restrict__ gsum, const int* __restrict__ batch,
                                               const float* __restrict__ stats,
                                               const float* __restrict__ gamma, const float* __restrict__ beta,
                                               const float* __restrict__ Wfc, const float* __restrict__ bfc,
                                               float* __restrict__ feats) {
  __shared__ float pv[512];
  __shared__ float red[4][64];
  int g = blockIdx.x;
  int t = threadIdx.x;
  int r0 = lower_bound_dev(batch, g);
  int r1 = lower_bound_dev(batch, g + 1);
  float inv = 1.f / fmaxf((float)(r1 - r0), 1.f);
#pragma unroll
  for (int r = 0; r < 2; ++r) {
    int c = t + r * 256;
    float s = 0.f, qv = 0.f;
#pragma unroll
    for (int b = 0; b < NBUCK; ++b) {
      s += stats[b * 1024 + c];
      qv += stats[b * 1024 + 512 + c];
    }
    float mean = s * (1.f / NODES);
    float var = qv * (1.f / NODES) - mean * mean;
    float sc = gamma[c] * rsqrtf(var + BN_EPS);
    float sh = beta[c] - mean * sc;
    pv[c] = gsum[g * DD + c] * inv * sc + sh;
  }
  __syncthreads();
  int colc = blockIdx.y * 64 + (t & 63);
  int kc = t >> 6;                      // 0..3
  float p = 0.f;
  int k0 = kc * 128;
  for (int k = k0; k < k0 + 128; ++k)
    p = fmaf(pv[k], Wfc[k * DD + colc], p);
  red[kc][t & 63] = p;
  __syncthreads();
  if (t < 64) {
    int c = blockIdx.y * 64 + t;
    float v = red[0][t] + red[1][t] + red[2][t] + red[3][t] + bfc[c];
    feats[g * DD + c] = tanhf(v);
  }
}

// ---- logits: grid (GRAPHS, NOUT), 64-lane wave reduction ----
__global__ __launch_bounds__(64) void k_logits2(const float* __restrict__ feats, const float* __restrict__ Wlog,
                                                const float* __restrict__ blog, float* __restrict__ out) {
  int g = blockIdx.x, o = blockIdx.y;
  int lane = threadIdx.x;
  float p = 0.f;
  for (int k = lane; k < DD; k += 64)
    p = fmaf(feats[g * DD + k], Wlog[k * NOUT + o], p);
#pragma unroll
  for (int off = 32; off > 0; off >>= 1)
    p += __shfl_down(p, off);
  if (lane == 0) out[g * NOUT + o] = p + blog[o];
}

extern "C" void kernel_launch(void* const* d_in, const int* in_sizes, int n_in,
                              void* d_out, int out_size, void* d_ws, size_t ws_size,
                              hipStream_t stream) {
  const float* x = (const float*)d_in[0];
  const int* ei = (const int*)d_in[1];
  const int* batch = (const int*)d_in[2];
  const float* W1a = (const float*)d_in[3];
  const float* b1a = (const float*)d_in[4];
  const float* W1b = (const float*)d_in[5];
  const float* b1b = (const float*)d_in[6];
  const float* Wa = (const float*)d_in[7];
  const float* ba = (const float*)d_in[8];
  const float* Wb = (const float*)d_in[9];
  const float* bb = (const float*)d_in[10];
  const float* bng = (const float*)d_in[11];
  const float* bnb = (const float*)d_in[12];
  const float* Wfc = (const float*)d_in[13];
  const float* bfc = (const float*)d_in[14];
  const float* Wlog = (const float*)d_in[15];
  const float* blog = (const float*)d_in[16];
  float* out = (float*)d_out;

  const int* src = ei;
  const int* dstp = ei + EDGES;

  char* w = (char*)d_ws;
  int* rowptr  = (int*)(w);                 // 10001 i32 (pad 40192)
  int* cur     = (int*)(w + 40192);         // 10000 i32
  int* col     = (int*)(w + 80384);         // 160000 i32 -> ends 720384
  float* bns   = (float*)(w + 720384);      // 5 x NBUCK x 1024 f = 40960 f
  float* gsum  = (float*)(w + 884224);      // 32768 f (contiguous after bns) -> ends 1015296
  float* feats = (float*)(w + 1015296);     // 32768 f -> ends 1146368
  int* bar     = (int*)(w + 1146368);       // 16 i32 -> ends 1146432
  u16* Wt      = (u16*)(w + 1146432);       // 9 x 262144 u16 = 4.72 MB -> ends 5865024
  u16* P0      = (u16*)(w + 5865024);       // 5,120,000 fp16
  u16* P1      = (u16*)(w + 16154176);      // 5,120,000 fp16 (end ~26.4 MB)

  // setup (zero cur + bns + gsum + bar) and CSR build
  k_setup<<<288, 256, 0, stream>>>(cur, bns, bar);
  k_count<<<625, 256, 0, stream>>>(dstp, cur);
  k_scan<<<1, 1024, 0, stream>>>(cur, rowptr);   // also resets cur to 0
  k_fill<<<625, 256, 0, stream>>>(src, dstp, rowptr, cur, col);

  // weight transpose to fp16 (9 DxD matrices)
  k_wsplit<<<dim3(16, 16, 9), 256, 0, stream>>>(W1b, Wa, Wb, Wt);

  // layer-1 input path
  k_l1<<<625, 256, 0, stream>>>(x, rowptr, col, W1a, b1a, P0);

  // mega-kernel: layer-1 gemm + layers 2..5, grid-synced internally
  k_net<<<NBLK, 256, 0, stream>>>(P0, P1, rowptr, col, Wt, b1b, ba, bb, bng, bnb, bns, bar);

  // pooling + head (layer-5 BN folded) + logits; final activations in P1
  k_pool_part<<<dim3(GRAPHS, 8), 128, 0, stream>>>(P1, batch, gsum);
  k_headf<<<dim3(GRAPHS, 8), 256, 0, stream>>>(gsum, batch, bns + (size_t)4 * NBUCK * 1024,
                                               bng + 4 * DD, bnb + 4 * DD, Wfc, bfc, feats);
  k_logits2<<<dim3(GRAPHS, NOUT), 64, 0, stream>>>(feats, Wlog, blog, out);
}

// Round 17
// 585.941 us; speedup vs baseline: 4.7288x; 4.7288x over previous
//
#include <hip/hip_runtime.h>

#define NODES 10000
#define EDGES 160000
#define INF_ 16
#define DD 512
#define GRAPHS 64
#define NOUT 18
#define BN_EPS 1e-5f
#define NBUCK 8

using u16 = unsigned short;
typedef __attribute__((ext_vector_type(8))) _Float16 f16x8;
typedef __attribute__((ext_vector_type(4))) float f32x4;

__device__ __forceinline__ float h2f(u16 u) {
  union { u16 u; _Float16 h; } v; v.u = u; return (float)v.h;
}
__device__ __forceinline__ u16 f2h(float f) {
  union { u16 u; _Float16 h; } v; v.h = (_Float16)f; return v.u;
}
__device__ __forceinline__ void add8(uint4 u, float* a) {
  a[0] += h2f((u16)(u.x & 0xffff)); a[1] += h2f((u16)(u.x >> 16));
  a[2] += h2f((u16)(u.y & 0xffff)); a[3] += h2f((u16)(u.y >> 16));
  a[4] += h2f((u16)(u.z & 0xffff)); a[5] += h2f((u16)(u.z >> 16));
  a[6] += h2f((u16)(u.w & 0xffff)); a[7] += h2f((u16)(u.w >> 16));
}
__device__ __forceinline__ unsigned int pk(float a, float b) {
  return (unsigned int)f2h(a) | ((unsigned int)f2h(b) << 16);
}
__device__ __forceinline__ int lower_bound_dev(const int* __restrict__ batch, int g) {
  int lo = 0, hi = NODES;
  while (lo < hi) { int m = (lo + hi) >> 1; if (batch[m] < g) lo = m + 1; else hi = m; }
  return lo;
}

// ---- setup: zero cur (10000 i32) + bns|gsum (73728 f) ----
__global__ void k_setup(int* __restrict__ cur, float* __restrict__ bg) {
  int i = blockIdx.x * 256 + threadIdx.x;
  if (i < NODES) cur[i] = 0;
  if (i < 73728) bg[i] = 0.f;
}

// ---- CSR build (dst-indexed): count -> scan(+reset) -> fill ----
__global__ void k_count(const int* __restrict__ dst, int* __restrict__ cnt) {
  int e = blockIdx.x * 256 + threadIdx.x;
  if (e < EDGES) atomicAdd(&cnt[dst[e]], 1);
}

__global__ __launch_bounds__(1024) void k_scan(int* __restrict__ cnt, int* __restrict__ rowptr) {
  __shared__ int s[1024];
  int t = threadIdx.x;
  int base = t * 10;
  int c[10]; int sum = 0;
#pragma unroll
  for (int i = 0; i < 10; ++i) {
    int idx = base + i;
    c[i] = (idx < NODES) ? cnt[idx] : 0;
    if (idx < NODES) cnt[idx] = 0;   // reset for k_fill's running cursor
    sum += c[i];
  }
  s[t] = sum; __syncthreads();
  for (int off = 1; off < 1024; off <<= 1) {
    int v = s[t];
    int a = (t >= off) ? s[t - off] : 0;
    __syncthreads();
    s[t] = v + a;
    __syncthreads();
  }
  int run = (t == 0) ? 0 : s[t - 1];
#pragma unroll
  for (int i = 0; i < 10; ++i) { int idx = base + i; if (idx < NODES) rowptr[idx] = run; run += c[i]; }
  if (t == 1023) rowptr[NODES] = s[1023];
}

__global__ void k_fill(const int* __restrict__ src, const int* __restrict__ dst,
                       const int* __restrict__ rowptr, int* __restrict__ cur, int* __restrict__ col) {
  int e = blockIdx.x * 256 + threadIdx.x;
  if (e < EDGES) {
    int d = dst[e];
    int p = atomicAdd(&cur[d], 1);
    col[rowptr[d] + p] = src[e];
  }
}

// ---- W transpose to fp16 [n][k]: Wt[n][k] = W[k][n] ----
__global__ __launch_bounds__(256) void k_wsplit(const float* __restrict__ W1b, const float* __restrict__ Wa,
                                                const float* __restrict__ Wb, u16* __restrict__ Wt) {
  __shared__ float tile[32][33];
  int z = blockIdx.z;
  const float* src = (z == 0) ? W1b : (z <= 4 ? Wa + (z - 1) * DD * DD : Wb + (z - 5) * DD * DD);
  int kb = blockIdx.y * 32, nb = blockIdx.x * 32;
  int tx = threadIdx.x & 31, ty = threadIdx.x >> 5;  // 32 x 8
#pragma unroll
  for (int i = 0; i < 4; ++i)
    tile[ty + 8 * i][tx] = src[(kb + ty + 8 * i) * DD + nb + tx];
  __syncthreads();
  u16* hi = Wt + (size_t)z * 262144;
#pragma unroll
  for (int i = 0; i < 4; ++i) {
    int n = nb + ty + 8 * i, k = kb + tx;
    hi[n * DD + k] = f2h(tile[tx][ty + 8 * i]);
  }
}

// ---- layer 1 fused: agg16 (LDS) + relu(h0 @ W1a + b1a), fp16 out ----
__global__ __launch_bounds__(256) void k_l1(const float* __restrict__ x, const int* __restrict__ rowptr,
                                            const int* __restrict__ col, const float* __restrict__ W1a,
                                            const float* __restrict__ b1a, u16* __restrict__ out) {
  __shared__ float sh0[16][17];
  int t = threadIdx.x;
  int nl = t >> 4, ch = t & 15;
  int node = blockIdx.x * 16 + nl;   // 625*16 = 10000 exact
  float acc = x[node * INF_ + ch];
  int r1 = rowptr[node + 1];
  for (int idx = rowptr[node]; idx < r1; ++idx)
    acc += x[col[idx] * INF_ + ch];
  sh0[nl][ch] = acc;
  __syncthreads();
#pragma unroll
  for (int p = 0; p < 2; ++p) {
    int c = t + 256 * p;
    float wreg[16];
#pragma unroll
    for (int k = 0; k < 16; ++k) wreg[k] = W1a[k * DD + c];
    float bv = b1a[c];
#pragma unroll
    for (int r = 0; r < 16; ++r) {
      float s = bv;
#pragma unroll
      for (int k = 0; k < 16; ++k) s = fmaf(sh0[r][k], wreg[k], s);
      out[(size_t)(blockIdx.x * 16 + r) * DD + c] = f2h(fmaxf(s, 0.f));
    }
  }
}

// ---- fused aggregation + BN(finalize from bucketed stats) + apply, [NODES,512] fp16 ----
__global__ __launch_bounds__(256) void k_agg512_bn(const u16* __restrict__ h, const int* __restrict__ rowptr,
                                                   const int* __restrict__ col, const float* __restrict__ stats,
                                                   const float* __restrict__ gamma, const float* __restrict__ beta,
                                                   u16* __restrict__ out) {
  __shared__ float ssc[512], ssh[512];
  int t = threadIdx.x;
#pragma unroll
  for (int r = 0; r < 2; ++r) {
    int c = t + r * 256;
    float s = 0.f, qv = 0.f;
#pragma unroll
    for (int b = 0; b < NBUCK; ++b) {
      s += stats[b * 1024 + c];
      qv += stats[b * 1024 + 512 + c];
    }
    float mean = s * (1.f / NODES);
    float var = qv * (1.f / NODES) - mean * mean;
    float sc = gamma[c] * rsqrtf(var + BN_EPS);
    ssc[c] = sc;
    ssh[c] = beta[c] - mean * sc;
  }
  __syncthreads();

  int lane = t & 63;
  int node = blockIdx.x * 4 + (t >> 6);   // grid 2500 x 4 = 10000 exact
  int c8 = lane * 8;
  float sc[8], sh[8];
#pragma unroll
  for (int k = 0; k < 8; ++k) { sc[k] = ssc[c8 + k]; sh[k] = ssh[c8 + k]; }

  const u16* hp = h + c8;
  float acc[8];
  {
    uint4 sv = *(const uint4*)(hp + (size_t)node * DD);
    acc[0] = h2f((u16)(sv.x & 0xffff)); acc[1] = h2f((u16)(sv.x >> 16));
    acc[2] = h2f((u16)(sv.y & 0xffff)); acc[3] = h2f((u16)(sv.y >> 16));
    acc[4] = h2f((u16)(sv.z & 0xffff)); acc[5] = h2f((u16)(sv.z >> 16));
    acc[6] = h2f((u16)(sv.w & 0xffff)); acc[7] = h2f((u16)(sv.w >> 16));
  }
  int r0 = rowptr[node], r1 = rowptr[node + 1];
  int idx = r0;
  for (; idx + 3 < r1; idx += 4) {
    int j0 = col[idx], j1 = col[idx + 1], j2 = col[idx + 2], j3 = col[idx + 3];
    uint4 a = *(const uint4*)(hp + (size_t)j0 * DD);
    uint4 b = *(const uint4*)(hp + (size_t)j1 * DD);
    uint4 c = *(const uint4*)(hp + (size_t)j2 * DD);
    uint4 d = *(const uint4*)(hp + (size_t)j3 * DD);
    add8(a, acc); add8(b, acc); add8(c, acc); add8(d, acc);
  }
  for (; idx < r1; ++idx) {
    int j = col[idx];
    uint4 a = *(const uint4*)(hp + (size_t)j * DD);
    add8(a, acc);
  }
  float n = (float)(r1 - r0 + 1);
  uint4 o;
  o.x = pk(sc[0] * acc[0] + n * sh[0], sc[1] * acc[1] + n * sh[1]);
  o.y = pk(sc[2] * acc[2] + n * sh[2], sc[3] * acc[3] + n * sh[3]);
  o.z = pk(sc[4] * acc[4] + n * sh[4], sc[5] * acc[5] + n * sh[5]);
  o.w = pk(sc[6] * acc[6] + n * sh[6], sc[7] * acc[7] + n * sh[7]);
  *(uint4*)(out + (size_t)node * DD + c8) = o;
}

// ---- MFMA GEMM: C[M,512] = relu(A[M,512](fp16) @ W[512,512](fp16,[n][k]) + bias), fp16 out ----
// LDS-staged, register-prefetch pipeline; 1-D grid 628 XCD-swizzled (4 bn-blocks of a bm-slab
// share an XCD). BM=64 BN=128 BK=64. STATS=1: bucketed block-reduced BN stats.
template <int STATS>
__global__ __launch_bounds__(256, 4) void mfma_gemm(
    const u16* __restrict__ A, const u16* __restrict__ Wt,
    const float* __restrict__ bias, u16* __restrict__ C, int M,
    float* __restrict__ stats) {
  __shared__ u16 lds[13824];           // 27648 B
  u16* As = lds;                       // [64][72]
  u16* Wh = lds + 4608;                // [128][72]
  const int T = threadIdx.x;
  int id = blockIdx.x;
  int bm_i, bn_i;
  if (id < 608) { int gi = id >> 5, r = id & 31; bm_i = gi * 8 + (r & 7); bn_i = r >> 3; }
  else { int r = id - 608; bm_i = 152 + (r % 5); bn_i = r / 5; }
  const int bm = bm_i * 64;
  const int bn = bn_i * 128;
  const int lane = T & 63;
  const int wave = T >> 6;
  const int wm = (wave & 1) * 32;
  const int wn = (wave >> 1) * 64;
  const int q = lane >> 4;
  const int r16 = lane & 15;

  const int arow0 = bm + (T >> 3);
  const int akc = (T & 7) * 8;
  f32x4 acc[2][4] = {};

  uint4 ra[2], rw[4];
#pragma unroll
  for (int p = 0; p < 2; ++p) {
    int grow = arow0 + p * 32;
    ra[p] = make_uint4(0u, 0u, 0u, 0u);
    if (grow < M) ra[p] = *(const uint4*)(A + (size_t)grow * DD + akc);
  }
#pragma unroll
  for (int p = 0; p < 4; ++p) {
    int row = (T + 256 * p) >> 3;
    rw[p] = *(const uint4*)(Wt + (size_t)(bn + row) * DD + akc);
  }

  for (int k0 = 0; k0 < 512; k0 += 64) {
#pragma unroll
    for (int p = 0; p < 2; ++p) {
      int row = (T >> 3) + p * 32;
      *(uint4*)(As + row * 72 + akc) = ra[p];
    }
#pragma unroll
    for (int p = 0; p < 4; ++p) {
      int row = (T + 256 * p) >> 3;
      *(uint4*)(Wh + row * 72 + akc) = rw[p];
    }
    __syncthreads();
    if (k0 + 64 < 512) {
      int kn = k0 + 64;
#pragma unroll
      for (int p = 0; p < 2; ++p) {
        int grow = arow0 + p * 32;
        ra[p] = make_uint4(0u, 0u, 0u, 0u);
        if (grow < M) ra[p] = *(const uint4*)(A + (size_t)grow * DD + kn + akc);
      }
#pragma unroll
      for (int p = 0; p < 4; ++p) {
        int row = (T + 256 * p) >> 3;
        rw[p] = *(const uint4*)(Wt + (size_t)(bn + row) * DD + kn + akc);
      }
    }
#pragma unroll
    for (int ks = 0; ks < 2; ++ks) {
      int kb = ks * 32 + q * 8;
      f16x8 af[2], bh[4];
#pragma unroll
      for (int mt = 0; mt < 2; ++mt)
        af[mt] = *(const f16x8*)(As + (wm + mt * 16 + r16) * 72 + kb);
#pragma unroll
      for (int nt = 0; nt < 4; ++nt)
        bh[nt] = *(const f16x8*)(Wh + (wn + nt * 16 + r16) * 72 + kb);
#pragma unroll
      for (int mt = 0; mt < 2; ++mt)
#pragma unroll
        for (int nt = 0; nt < 4; ++nt)
          acc[mt][nt] = __builtin_amdgcn_mfma_f32_16x16x32_f16(af[mt], bh[nt], acc[mt][nt], 0, 0, 0);
    }
    __syncthreads();
  }

  // epilogue: bias + relu + fp16 store (+ optional block-reduced BN stats)
  float colS[4] = {}, colQ[4] = {};
#pragma unroll
  for (int nt = 0; nt < 4; ++nt) {
    int n = bn + wn + nt * 16 + r16;
    float bv = bias[n];
#pragma unroll
    for (int mt = 0; mt < 2; ++mt) {
#pragma unroll
      for (int rr = 0; rr < 4; ++rr) {
        int row = bm + wm + mt * 16 + q * 4 + rr;
        if (row < M) {
          float v = fmaxf(acc[mt][nt][rr] + bv, 0.f);
          C[(size_t)row * DD + n] = f2h(v);
          if (STATS) { colS[nt] += v; colQ[nt] += v * v; }
        }
      }
    }
  }
  if (STATS) {
#pragma unroll
    for (int nt = 0; nt < 4; ++nt) {
      colS[nt] += __shfl_xor(colS[nt], 16); colS[nt] += __shfl_xor(colS[nt], 32);
      colQ[nt] += __shfl_xor(colQ[nt], 16); colQ[nt] += __shfl_xor(colQ[nt], 32);
    }
    float* lsum = (float*)lds;          // [4][64]
    float* lsq = lsum + 256;            // [4][64]
    if (q == 0) {
#pragma unroll
      for (int nt = 0; nt < 4; ++nt) {
        lsum[wave * 64 + nt * 16 + r16] = colS[nt];
        lsq[wave * 64 + nt * 16 + r16] = colQ[nt];
      }
    }
    __syncthreads();
    if (T < 128) {
      int c = T;
      int wb = (c >> 6) << 1;
      int cc = c & 63;
      float s = lsum[wb * 64 + cc] + lsum[(wb + 1) * 64 + cc];
      float qv = lsq[wb * 64 + cc] + lsq[(wb + 1) * 64 + cc];
      float* sb = stats + (size_t)(bm_i & (NBUCK - 1)) * 1024;
      atomicAdd(&sb[bn + c], s);
      atomicAdd(&sb[512 + bn + c], qv);
    }
  }
}

// ---- pooled partial sums: grid (GRAPHS, 8 slices), per-block binary-search bounds ----
__global__ __launch_bounds__(128) void k_pool_part(const u16* __restrict__ h, const int* __restrict__ batch,
                                                   float* __restrict__ gsum) {
  int g = blockIdx.x;
  int s = blockIdx.y;
  int c4 = threadIdx.x * 4;
  int r0 = lower_bound_dev(batch, g);
  int r1 = lower_bound_dev(batch, g + 1);
  int cnt = r1 - r0;
  int len = (cnt + 7) >> 3;
  int rs = r0 + s * len;
  int re = min(rs + len, r1);
  if (rs >= re) return;
  float4 acc = make_float4(0.f, 0.f, 0.f, 0.f);
  for (int r = rs; r < re; ++r) {
    ushort4 v = *(const ushort4*)(h + (size_t)r * DD + c4);
    acc.x += h2f(v.x); acc.y += h2f(v.y); acc.z += h2f(v.z); acc.w += h2f(v.w);
  }
  atomicAdd(&gsum[g * DD + c4 + 0], acc.x);
  atomicAdd(&gsum[g * DD + c4 + 1], acc.y);
  atomicAdd(&gsum[g * DD + c4 + 2], acc.z);
  atomicAdd(&gsum[g * DD + c4 + 3], acc.w);
}

// ---- head: feats = tanh(bn(mean) @ Wfc + bfc); grid (GRAPHS, 8 col-slices), K split 4-way ----
__global__ __launch_bounds__(256) void k_headf(const float* __restrict__ gsum, const int* __restrict__ batch,
                                               const float* __restrict__ stats,
                                               const float* __restrict__ gamma, const float* __restrict__ beta,
                                               const float* __restrict__ Wfc, const float* __restrict__ bfc,
                                               float* __restrict__ feats) {
  __shared__ float pv[512];
  __shared__ float red[4][64];
  int g = blockIdx.x;
  int t = threadIdx.x;
  int r0 = lower_bound_dev(batch, g);
  int r1 = lower_bound_dev(batch, g + 1);
  float inv = 1.f / fmaxf((float)(r1 - r0), 1.f);
#pragma unroll
  for (int r = 0; r < 2; ++r) {
    int c = t + r * 256;
    float s = 0.f, qv = 0.f;
#pragma unroll
    for (int b = 0; b < NBUCK; ++b) {
      s += stats[b * 1024 + c];
      qv += stats[b * 1024 + 512 + c];
    }
    float mean = s * (1.f / NODES);
    float var = qv * (1.f / NODES) - mean * mean;
    float sc = gamma[c] * rsqrtf(var + BN_EPS);
    float sh = beta[c] - mean * sc;
    pv[c] = gsum[g * DD + c] * inv * sc + sh;
  }
  __syncthreads();
  int colc = blockIdx.y * 64 + (t & 63);
  int kc = t >> 6;                      // 0..3
  float p = 0.f;
  int k0 = kc * 128;
  for (int k = k0; k < k0 + 128; ++k)
    p = fmaf(pv[k], Wfc[k * DD + colc], p);
  red[kc][t & 63] = p;
  __syncthreads();
  if (t < 64) {
    int c = blockIdx.y * 64 + t;
    float v = red[0][t] + red[1][t] + red[2][t] + red[3][t] + bfc[c];
    feats[g * DD + c] = tanhf(v);
  }
}

// ---- logits: grid (GRAPHS, NOUT), 64-lane wave reduction ----
__global__ __launch_bounds__(64) void k_logits2(const float* __restrict__ feats, const float* __restrict__ Wlog,
                                                const float* __restrict__ blog, float* __restrict__ out) {
  int g = blockIdx.x, o = blockIdx.y;
  int lane = threadIdx.x;
  float p = 0.f;
  for (int k = lane; k < DD; k += 64)
    p = fmaf(feats[g * DD + k], Wlog[k * NOUT + o], p);
#pragma unroll
  for (int off = 32; off > 0; off >>= 1)
    p += __shfl_down(p, off);
  if (lane == 0) out[g * NOUT + o] = p + blog[o];
}

extern "C" void kernel_launch(void* const* d_in, const int* in_sizes, int n_in,
                              void* d_out, int out_size, void* d_ws, size_t ws_size,
                              hipStream_t stream) {
  const float* x = (const float*)d_in[0];
  const int* ei = (const int*)d_in[1];
  const int* batch = (const int*)d_in[2];
  const float* W1a = (const float*)d_in[3];
  const float* b1a = (const float*)d_in[4];
  const float* W1b = (const float*)d_in[5];
  const float* b1b = (const float*)d_in[6];
  const float* Wa = (const float*)d_in[7];
  const float* ba = (const float*)d_in[8];
  const float* Wb = (const float*)d_in[9];
  const float* bb = (const float*)d_in[10];
  const float* bng = (const float*)d_in[11];
  const float* bnb = (const float*)d_in[12];
  const float* Wfc = (const float*)d_in[13];
  const float* bfc = (const float*)d_in[14];
  const float* Wlog = (const float*)d_in[15];
  const float* blog = (const float*)d_in[16];
  float* out = (float*)d_out;

  const int* src = ei;
  const int* dstp = ei + EDGES;

  char* w = (char*)d_ws;
  int* rowptr  = (int*)(w);                 // 10001 i32 (pad 40192)
  int* cur     = (int*)(w + 40192);         // 10000 i32
  int* col     = (int*)(w + 80384);         // 160000 i32 -> ends 720384
  float* bns   = (float*)(w + 720384);      // 5 x NBUCK x 1024 f = 40960 f
  float* gsum  = (float*)(w + 884224);      // 32768 f (contiguous after bns) -> ends 1015296
  float* feats = (float*)(w + 1015296);     // 32768 f -> ends 1146368
  u16* Wt      = (u16*)(w + 1146368);       // 9 x 262144 u16 = 4.72 MB -> ends 5864960
  u16* P0      = (u16*)(w + 5864960);       // 5,120,000 fp16
  u16* P1      = (u16*)(w + 16154112);      // 5,120,000 fp16 (end ~26.4 MB)

  // setup (zero cur + bns + gsum) and CSR build
  k_setup<<<288, 256, 0, stream>>>(cur, bns);
  k_count<<<625, 256, 0, stream>>>(dstp, cur);
  k_scan<<<1, 1024, 0, stream>>>(cur, rowptr);   // also resets cur to 0
  k_fill<<<625, 256, 0, stream>>>(src, dstp, rowptr, cur, col);

  // weight transpose to fp16 (9 DxD matrices)
  k_wsplit<<<dim3(16, 16, 9), 256, 0, stream>>>(W1b, Wa, Wb, Wt);

  // layer 1: fused agg16 + K16 gemm -> P0, then big gemm + stats
  k_l1<<<625, 256, 0, stream>>>(x, rowptr, col, W1a, b1a, P0);
  mfma_gemm<1><<<628, 256, 0, stream>>>(P0, Wt, b1b, P1, NODES, bns);

  // layers 2..5: H -> agg+bn -> T -> mfma(Wa) -> H -> mfma(Wb)+stats -> T
  u16* H = P1;
  u16* T = P0;
  for (int i = 0; i < 4; ++i) {
    k_agg512_bn<<<2500, 256, 0, stream>>>(H, rowptr, col, bns + (size_t)i * NBUCK * 1024,
                                          bng + i * DD, bnb + i * DD, T);
    mfma_gemm<0><<<628, 256, 0, stream>>>(T, Wt + (size_t)(1 + i) * 262144, ba + i * DD, H, NODES, nullptr);
    mfma_gemm<1><<<628, 256, 0, stream>>>(H, Wt + (size_t)(5 + i) * 262144, bb + i * DD, T, NODES,
                                          bns + (size_t)(i + 1) * NBUCK * 1024);
    u16* tmp = H; H = T; T = tmp;
  }

  // pooling + head (layer-5 BN folded) + logits
  k_pool_part<<<dim3(GRAPHS, 8), 128, 0, stream>>>(H, batch, gsum);
  k_headf<<<dim3(GRAPHS, 8), 256, 0, stream>>>(gsum, batch, bns + (size_t)4 * NBUCK * 1024,
                                               bng + 4 * DD, bnb + 4 * DD, Wfc, bfc, feats);
  k_logits2<<<dim3(GRAPHS, NOUT), 64, 0, stream>>>(feats, Wlog, blog, out);
}